// Round 10
// baseline (466.306 us; speedup 1.0000x reference)
//
#include <hip/hip_runtime.h>
#include <math.h>

#define NN 50000
#define EE 800000
#define ET (EE + NN)                 // 850000 edges incl self-loops
#define NCHK ((NN + 255) / 256)      // 196 scan chunks
#define NEG 0.2f

__device__ __forceinline__ float lrelu(float x) { return x > 0.f ? x : NEG * x; }

typedef __bf16 bf16x8 __attribute__((ext_vector_type(8)));
typedef float f32x4 __attribute__((ext_vector_type(4)));

// ---------------- CSR build (counting sort by dst) ----------------

__global__ __launch_bounds__(256) void k_hist(const int* __restrict__ eidx, int* __restrict__ cnt) {
    int i = blockIdx.x * 256 + threadIdx.x;
    if (i < EE) atomicAdd(&cnt[eidx[EE + i]], 1);
}

__global__ __launch_bounds__(256) void k_csum(const int* __restrict__ cnt, int* __restrict__ csums) {
    __shared__ int sh[256];
    int t = threadIdx.x, i = blockIdx.x * 256 + t;
    sh[t] = (i < NN) ? cnt[i] + 1 : 0;
    __syncthreads();
    for (int off = 128; off > 0; off >>= 1) {
        if (t < off) sh[t] += sh[t + off];
        __syncthreads();
    }
    if (t == 0) csums[blockIdx.x] = sh[0];
}

__global__ __launch_bounds__(256) void k_chscan(const int* __restrict__ cnt, const int* __restrict__ csums,
                                                int* __restrict__ rowptr, int* __restrict__ cursor) {
    __shared__ int sh[256];
    __shared__ int shc[256];
    int t = threadIdx.x, b = blockIdx.x, i = b * 256 + t;
    int v = (i < NN) ? cnt[i] + 1 : 0;
    sh[t] = v;
    shc[t] = (t < NCHK) ? csums[t] : 0;
    __syncthreads();
    for (int off = 1; off < 256; off <<= 1) {
        int x1 = (t >= off) ? sh[t - off] : 0;
        int x2 = (t >= off) ? shc[t - off] : 0;
        __syncthreads();
        sh[t] += x1;
        shc[t] += x2;
        __syncthreads();
    }
    int cbase = (b == 0) ? 0 : shc[b - 1];
    int ex = (t == 0 ? 0 : sh[t - 1]) + cbase;
    if (i < NN) { rowptr[i] = ex; cursor[i] = ex; }
    if (b == 0 && t == 0) rowptr[NN] = ET;
}

__global__ __launch_bounds__(256) void k_scatter(const int* __restrict__ eidx,
                                                 int* __restrict__ cursor, int* __restrict__ ssrc) {
    int i = blockIdx.x * 256 + threadIdx.x;
    if (i >= ET) return;
    int s, d;
    if (i < EE) { s = eidx[i]; d = eidx[EE + i]; } else { s = d = i - EE; }
    int pos = atomicAdd(&cursor[d], 1);
    ssrc[pos] = s;
}

// ---------------- W pre-split + attention columns, padded B-fragment order ----------------
// Padded width NOUTP = NOUT+16. Cols NOUT..NOUT+3 = Wa (es per head), NOUT+4..NOUT+7 = Wd
// (ed per head), rest zero.  Wa[k,h] = sum_c W[k,h*CH+c]*asrc[h,c]  (es is linear in x).

__global__ __launch_bounds__(256) void k_wsplit2(const float* __restrict__ W0, const float* __restrict__ W1,
                                                 const float* __restrict__ W2, const float* __restrict__ W3,
                                                 const float* __restrict__ as0, const float* __restrict__ as1,
                                                 const float* __restrict__ as2, const float* __restrict__ as3,
                                                 const float* __restrict__ ad0, const float* __restrict__ ad1,
                                                 const float* __restrict__ ad2, const float* __restrict__ ad3,
                                                 __bf16* __restrict__ wsp) {
    int i = blockIdx.x * 256 + threadIdx.x;
    const float *Wm, *asv, *adv; int NOUT, CH, j; size_t base, sz;
    if (i < 18432)      { Wm = W0; asv = as0; adv = ad0; NOUT = 128; CH = 32; j = i;          base = 0;      sz = 18432; }
    else if (i < 36864) { Wm = W1; asv = as1; adv = ad1; NOUT = 128; CH = 32; j = i - 18432;  base = 36864;  sz = 18432; }
    else if (i < 55296) { Wm = W2; asv = as2; adv = ad2; NOUT = 128; CH = 32; j = i - 36864;  base = 73728;  sz = 18432; }
    else if (i < 77824) { Wm = W3; asv = as3; adv = ad3; NOUT = 160; CH = 40; j = i - 55296;  base = 110592; sz = 22528; }
    else return;
    int NOUTP = NOUT + 16;
    int k = j / NOUTP, c = j - k * NOUTP;
    float v;
    if (c < NOUT) {
        v = Wm[k * NOUT + c];
    } else if (c < NOUT + 8) {
        int h = (c - NOUT) & 3;
        const float* av = (c < NOUT + 4) ? asv : adv;
        float sacc = 0.f;
        for (int cc = 0; cc < CH; ++cc) sacc += Wm[k * NOUT + h * CH + cc] * av[h * CH + cc];
        v = sacc;
    } else {
        v = 0.f;
    }
    __bf16 hi = (__bf16)v;
    __bf16 lo = (__bf16)(v - (float)hi);
    size_t off = base + ((size_t)(k >> 3) * NOUTP + c) * 8 + (k & 7);
    wsp[off] = hi;
    wsp[off + sz] = lo;
}

// ---------------- split-bf16 MFMA GEMM, 16 rows/wave (2x occupancy), es/ed via extra tile ----------------
// block = 4 waves x 16 rows = 64 rows; grid 782 -> ~3 waves/SIMD resident (was 1.5).
// A frag: row = l&15, k = (l>>4)*8+j.  B frag: col = l&15, same k (16B/lane, L2-hot).
// C/D: col = l&15, row = (l>>4)*4+i  [m89-verified].

template <int NOUT>
__global__ __launch_bounds__(256) void k_gemm5(const float* __restrict__ X,
                                               const __bf16* __restrict__ Whi,
                                               const __bf16* __restrict__ Wlo,
                                               float* __restrict__ Y,
                                               float* __restrict__ es, float* __restrict__ ed) {
    constexpr int NT = NOUT / 16;
    constexpr int NTP = NT + 1;            // +1 tile: cols 0-3 es, 4-7 ed, 8-15 zero
    constexpr int NOUTP = NOUT + 16;
    int tid = threadIdx.x;
    int w = tid >> 6, l = tid & 63;
    int col = l & 15, kg = l >> 4;
    int rb = blockIdx.x * 64 + w * 16;
    int r0 = rb + col;
    int rc0 = r0 < NN ? r0 : NN - 1;

    f32x4 acc0[NTP];
    #pragma unroll
    for (int t = 0; t < NTP; ++t) acc0[t] = (f32x4){0, 0, 0, 0};

    #pragma unroll
    for (int c4 = 0; c4 < 4; ++c4) {
        bf16x8 ah0, al0;
        {
            float4 aA = *reinterpret_cast<const float4*>(&X[(size_t)rc0 * 128 + c4 * 32 + kg * 8]);
            float4 aB = *reinterpret_cast<const float4*>(&X[(size_t)rc0 * 128 + c4 * 32 + kg * 8 + 4]);
            float av[8] = {aA.x, aA.y, aA.z, aA.w, aB.x, aB.y, aB.z, aB.w};
            #pragma unroll
            for (int j = 0; j < 8; ++j) { __bf16 h = (__bf16)av[j]; ah0[j] = h; al0[j] = (__bf16)(av[j] - (float)h); }
        }
        const __bf16* bh = Whi + ((size_t)(c4 * 4 + kg) * NOUTP) * 8;
        const __bf16* bl = Wlo + ((size_t)(c4 * 4 + kg) * NOUTP) * 8;
        #pragma unroll
        for (int t = 0; t < NTP; ++t) {
            bf16x8 bhi = *reinterpret_cast<const bf16x8*>(bh + (t * 16 + col) * 8);
            bf16x8 blo = *reinterpret_cast<const bf16x8*>(bl + (t * 16 + col) * 8);
            acc0[t] = __builtin_amdgcn_mfma_f32_16x16x32_bf16(ah0, bhi, acc0[t], 0, 0, 0);
            acc0[t] = __builtin_amdgcn_mfma_f32_16x16x32_bf16(al0, bhi, acc0[t], 0, 0, 0);
            acc0[t] = __builtin_amdgcn_mfma_f32_16x16x32_bf16(ah0, blo, acc0[t], 0, 0, 0);
        }
    }

    #pragma unroll
    for (int t = 0; t < NT; ++t) {
        int cc = t * 16 + col;
        #pragma unroll
        for (int i = 0; i < 4; ++i) {
            int ra = rb + kg * 4 + i;
            if (ra < NN) Y[(size_t)ra * NOUT + cc] = acc0[t][i];
        }
    }
    #pragma unroll
    for (int i = 0; i < 4; ++i) {
        int ra = rb + kg * 4 + i;
        if (ra < NN) {
            if (col < 4)      es[ra * 4 + col] = acc0[NT][i];
            else if (col < 8) ed[ra * 4 + col - 4] = acc0[NT][i];
        }
    }
}

// ---------------- single-pass wave-per-node aggregation (no-max softmax) ----------------
// Logits e = lrelu(es+ed) are O(1) -> exp(e) cannot overflow f32; alpha = exp(e)/sum
// is mathematically identical to the reference's max-shifted form.

__global__ __launch_bounds__(256) void k_agg128(const float* __restrict__ Hf,
                                                const float* __restrict__ es, const float* __restrict__ ed,
                                                const int* __restrict__ rowptr, const int* __restrict__ ssrc,
                                                const float* __restrict__ bias, float* __restrict__ Yout) {
    int wid = (blockIdx.x * 256 + threadIdx.x) >> 6;
    int lane = threadIdx.x & 63;
    if (wid >= NN) return;
    int n = wid;
    int beg = rowptr[n], end = rowptr[n + 1];
    int h1 = lane & 3;
    int eoff = lane >> 2;
    float edv = ed[n * 4 + h1];
    int q = lane & 7;
    int eg8 = lane >> 3;

    f32x4 acc4[4];
    #pragma unroll
    for (int i = 0; i < 4; ++i) acc4[i] = (f32x4){0.f, 0.f, 0.f, 0.f};
    float dsum = 0.f;

    int nch = (end - beg + 15) >> 4;
    int myIdx = beg + eoff;
    int s_cur = ssrc[myIdx < end ? myIdx : end - 1];
    float esv = es[s_cur * 4 + h1];
    for (int ch = 0; ch < nch; ++ch) {
        int nIdx = myIdx + 16;
        int s_nxt = ssrc[nIdx < end ? nIdx : end - 1];     // prefetch
        float e = lrelu(esv + edv);
        float p = (myIdx < end) ? __expf(e) : 0.f;
        dsum += p;
        #pragma unroll
        for (int hb = 0; hb < 2; ++hb) {
            int e16 = hb * 8 + eg8;
            int se = __shfl(s_cur, e16 * 4);
            const float* rowp = Hf + (size_t)se * 128 + q * 4;
            #pragma unroll
            for (int i = 0; i < 4; ++i) {
                float pp = __shfl(p, e16 * 4 + i);          // head of slot i*8+q is i
                float4 v = *reinterpret_cast<const float4*>(rowp + i * 32);
                acc4[i].x += pp * v.x;
                acc4[i].y += pp * v.y;
                acc4[i].z += pp * v.z;
                acc4[i].w += pp * v.w;
            }
        }
        float esv_n = es[s_nxt * 4 + h1];
        s_cur = s_nxt; esv = esv_n; myIdx = nIdx;
    }

    #pragma unroll
    for (int off = 4; off < 64; off <<= 1) dsum += __shfl_xor(dsum, off);
    float inv0 = 1.f / __shfl(dsum, 0);
    float inv1 = 1.f / __shfl(dsum, 1);
    float inv2 = 1.f / __shfl(dsum, 2);
    float inv3 = 1.f / __shfl(dsum, 3);

    #pragma unroll
    for (int off = 8; off < 64; off <<= 1) {
        #pragma unroll
        for (int i = 0; i < 4; ++i) {
            acc4[i].x += __shfl_xor(acc4[i].x, off);
            acc4[i].y += __shfl_xor(acc4[i].y, off);
            acc4[i].z += __shfl_xor(acc4[i].z, off);
            acc4[i].w += __shfl_xor(acc4[i].w, off);
        }
    }
    if (lane < 8) {
        float inv[4] = {inv0, inv1, inv2, inv3};
        #pragma unroll
        for (int i = 0; i < 4; ++i) {
            int c0 = 32 * i + 4 * lane;
            float4 bv = *reinterpret_cast<const float4*>(&bias[c0]);
            float4 o;
            o.x = fmaxf(acc4[i].x * inv[i] + bv.x, 0.f);
            o.y = fmaxf(acc4[i].y * inv[i] + bv.y, 0.f);
            o.z = fmaxf(acc4[i].z * inv[i] + bv.z, 0.f);
            o.w = fmaxf(acc4[i].w * inv[i] + bv.w, 0.f);
            *reinterpret_cast<float4*>(&Yout[(size_t)n * 128 + c0]) = o;
        }
    }
}

// layer 4 (FEAT=160, CLS=40): single-pass, head-mean + bias folded in, writes d_out.

__global__ __launch_bounds__(256) void k_agg160_mean(const float* __restrict__ Hf,
                                                     const float* __restrict__ es, const float* __restrict__ ed,
                                                     const int* __restrict__ rowptr, const int* __restrict__ ssrc,
                                                     const float* __restrict__ b4, float* __restrict__ out) {
    __shared__ float buf[4][160];
    __shared__ float bufd[4][4];
    int wid = (blockIdx.x * 256 + threadIdx.x) >> 6;
    int lane = threadIdx.x & 63;
    int w = threadIdx.x >> 6;
    if (wid >= NN) return;
    int n = wid;
    int beg = rowptr[n], end = rowptr[n + 1];
    int h1 = lane & 3;
    int eoff = lane >> 2;
    float edv = ed[n * 4 + h1];
    int q = lane & 7;
    int eg8 = lane >> 3;
    int hh[5];
    #pragma unroll
    for (int i = 0; i < 5; ++i) hh[i] = (i * 8 + q) / 10;

    f32x4 acc4[5];
    #pragma unroll
    for (int i = 0; i < 5; ++i) acc4[i] = (f32x4){0.f, 0.f, 0.f, 0.f};
    float dsum = 0.f;

    int nch = (end - beg + 15) >> 4;
    int myIdx = beg + eoff;
    int s_cur = ssrc[myIdx < end ? myIdx : end - 1];
    float esv = es[s_cur * 4 + h1];
    for (int ch = 0; ch < nch; ++ch) {
        int nIdx = myIdx + 16;
        int s_nxt = ssrc[nIdx < end ? nIdx : end - 1];
        float e = lrelu(esv + edv);
        float p = (myIdx < end) ? __expf(e) : 0.f;
        dsum += p;
        #pragma unroll
        for (int hb = 0; hb < 2; ++hb) {
            int e16 = hb * 8 + eg8;
            int se = __shfl(s_cur, e16 * 4);
            const float* rowp = Hf + (size_t)se * 160 + q * 4;
            #pragma unroll
            for (int i = 0; i < 5; ++i) {
                float pp = __shfl(p, e16 * 4 + hh[i]);
                float4 v = *reinterpret_cast<const float4*>(rowp + i * 32);
                acc4[i].x += pp * v.x;
                acc4[i].y += pp * v.y;
                acc4[i].z += pp * v.z;
                acc4[i].w += pp * v.w;
            }
        }
        float esv_n = es[s_nxt * 4 + h1];
        s_cur = s_nxt; esv = esv_n; myIdx = nIdx;
    }

    #pragma unroll
    for (int off = 4; off < 64; off <<= 1) dsum += __shfl_xor(dsum, off);

    #pragma unroll
    for (int off = 8; off < 64; off <<= 1) {
        #pragma unroll
        for (int i = 0; i < 5; ++i) {
            acc4[i].x += __shfl_xor(acc4[i].x, off);
            acc4[i].y += __shfl_xor(acc4[i].y, off);
            acc4[i].z += __shfl_xor(acc4[i].z, off);
            acc4[i].w += __shfl_xor(acc4[i].w, off);
        }
    }
    if (lane < 8) {
        #pragma unroll
        for (int i = 0; i < 5; ++i)
            *reinterpret_cast<float4*>(&buf[w][32 * i + 4 * lane]) = (float4){acc4[i].x, acc4[i].y, acc4[i].z, acc4[i].w};
    }
    if (lane < 4) bufd[w][lane] = 1.f / dsum;
    __builtin_amdgcn_wave_barrier();
    if (lane < 40) {
        float v = 0.25f * (buf[w][lane]       * bufd[w][0] +
                           buf[w][lane + 40]  * bufd[w][1] +
                           buf[w][lane + 80]  * bufd[w][2] +
                           buf[w][lane + 120] * bufd[w][3]) + b4[lane];
        out[(size_t)n * 40 + lane] = v;
    }
}

// ---------------- host launcher ----------------

extern "C" void kernel_launch(void* const* d_in, const int* in_sizes, int n_in,
                              void* d_out, int out_size, void* d_ws, size_t ws_size,
                              hipStream_t stream) {
    const float* x    = (const float*)d_in[0];
    const int*   eidx = (const int*)d_in[1];
    const float* W[4]    = {(const float*)d_in[2], (const float*)d_in[6], (const float*)d_in[10], (const float*)d_in[14]};
    const float* asrc[4] = {(const float*)d_in[3], (const float*)d_in[7], (const float*)d_in[11], (const float*)d_in[15]};
    const float* adst[4] = {(const float*)d_in[4], (const float*)d_in[8], (const float*)d_in[12], (const float*)d_in[16]};
    const float* bias[4] = {(const float*)d_in[5], (const float*)d_in[9], (const float*)d_in[13], (const float*)d_in[17]};
    float* out = (float*)d_out;

    // workspace layout
    float* hA = (float*)d_ws;                 // N*160
    float* hB = hA + (size_t)NN * 160;        // N*160
    float* es = hB + (size_t)NN * 160;        // N*4
    float* ed = es + (size_t)NN * 4;          // N*4
    int* rowptr = (int*)(ed + (size_t)NN * 4);  // N+1
    int* cnt    = rowptr + (NN + 1);            // N
    int* cursor = cnt + NN;                     // N
    int* ssrc   = cursor + NN;                  // ET
    int* csums  = ssrc + ET;                    // 256
    __bf16* wsp = (__bf16*)(csums + 256);       // padded split W + attn cols
    __bf16* Whi[4] = {wsp, wsp + 36864, wsp + 73728, wsp + 110592};
    __bf16* Wlo[4] = {wsp + 18432, wsp + 55296, wsp + 92160, wsp + 133120};

    // ---- CSR build (once; reused by all 4 layers) ----
    hipMemsetAsync(cnt, 0, NN * sizeof(int), stream);
    k_hist<<<(EE + 255) / 256, 256, 0, stream>>>(eidx, cnt);
    k_csum<<<NCHK, 256, 0, stream>>>(cnt, csums);
    k_chscan<<<NCHK, 256, 0, stream>>>(cnt, csums, rowptr, cursor);
    k_scatter<<<(ET + 255) / 256, 256, 0, stream>>>(eidx, cursor, ssrc);

    // ---- W pre-split + attention columns (one kernel) ----
    k_wsplit2<<<(77824 + 255) / 256, 256, 0, stream>>>(W[0], W[1], W[2], W[3],
                                                       asrc[0], asrc[1], asrc[2], asrc[3],
                                                       adst[0], adst[1], adst[2], adst[3], wsp);

    int gemmBlocks = (NN + 63) / 64;
    int aggBlocks = (NN * 64 + 255) / 256;

    // ---- layer 1: x -> hA (+es/ed) -> agg -> hB ----
    k_gemm5<128><<<gemmBlocks, 256, 0, stream>>>(x, Whi[0], Wlo[0], hA, es, ed);
    k_agg128<<<aggBlocks, 256, 0, stream>>>(hA, es, ed, rowptr, ssrc, bias[0], hB);

    // ---- layer 2 ----
    k_gemm5<128><<<gemmBlocks, 256, 0, stream>>>(hB, Whi[1], Wlo[1], hA, es, ed);
    k_agg128<<<aggBlocks, 256, 0, stream>>>(hA, es, ed, rowptr, ssrc, bias[1], hB);

    // ---- layer 3 ----
    k_gemm5<128><<<gemmBlocks, 256, 0, stream>>>(hB, Whi[2], Wlo[2], hA, es, ed);
    k_agg128<<<aggBlocks, 256, 0, stream>>>(hA, es, ed, rowptr, ssrc, bias[2], hB);

    // ---- layer 4: hB -> hA(160) (+es/ed) -> agg+mean -> out ----
    k_gemm5<160><<<gemmBlocks, 256, 0, stream>>>(hB, Whi[3], Wlo[3], hA, es, ed);
    k_agg160_mean<<<aggBlocks, 256, 0, stream>>>(hA, es, ed, rowptr, ssrc, bias[3], out);
}